// Round 5
// baseline (475.503 us; speedup 1.0000x reference)
//
#include <hip/hip_runtime.h>
#include <stdint.h>

typedef unsigned short ushort_t;
typedef __bf16 bf16x8 __attribute__((ext_vector_type(8)));
typedef float f32x4 __attribute__((ext_vector_type(4)));

#define T_TOK 8192
#define HDIM  1024
#define EXP   8
#define FDIM  2048
#define CAP   1280

// fp32 -> bf16 round-to-nearest-even
__device__ __forceinline__ unsigned short f2b(float f) {
  unsigned u = __float_as_uint(f);
  u = (u + 0x7fffu + ((u >> 16) & 1u)) >> 16;
  return (unsigned short)u;
}
__device__ __forceinline__ unsigned pk2(unsigned short lo, unsigned short hi) {
  return (unsigned)lo | ((unsigned)hi << 16);
}
// order-preserving fp32 -> u32 map (monotone increasing)
__device__ __forceinline__ unsigned map_u(float f) {
  unsigned u = __float_as_uint(f);
  return (u & 0x80000000u) ? ~u : (u | 0x80000000u);
}
__device__ __forceinline__ float unmap_f(unsigned m) {
  unsigned u = (m & 0x80000000u) ? (m ^ 0x80000000u) : ~m;
  return __uint_as_float(u);
}
// async global->LDS, 16B/lane; LDS dest = wave-uniform base + lane*16
__device__ __forceinline__ void gl_lds16(const void* g, void* l) {
  __builtin_amdgcn_global_load_lds((__attribute__((address_space(1))) void*)g,
                                   (__attribute__((address_space(3))) void*)l,
                                   16, 0, 0);
}

// --------------- prep: fused weight transpose+cast (w1,w3,w2) AND gating GEMV
// blocks [0,12288): transpose; blocks [12288,14336): gate+cast (independent work
// overlapped in one launch so the small gate kernel hides under the transpose).
__global__ void __launch_bounds__(256) prep_k(
    const float* __restrict__ w1, const float* __restrict__ w3, const float* __restrict__ w2,
    ushort_t* __restrict__ w1t, ushort_t* __restrict__ w3t, ushort_t* __restrict__ w2t,
    const float* __restrict__ x, const float* __restrict__ gw,
    float* __restrict__ logitsT, ushort_t* __restrict__ xb)
{
  __shared__ float tile[64][65];
  int bb = blockIdx.x;
  if (bb >= 12288) {
    // ---------------- gate + cast path
    int wave = threadIdx.x >> 6, lane = threadIdx.x & 63;
    int t = (bb - 12288) * 4 + wave;
    const float* xr = x + (size_t)t * HDIM;
    ushort_t* xbr = xb + (size_t)t * HDIM;
    float acc[8];
#pragma unroll
    for (int i = 0; i < 8; ++i) acc[i] = 0.f;
#pragma unroll
    for (int i = 0; i < 4; ++i) {
      int h0 = i * 256 + lane * 4;
      float4 xv = *(const float4*)(xr + h0);
      unsigned lo = pk2(f2b(xv.x), f2b(xv.y));
      unsigned hi = pk2(f2b(xv.z), f2b(xv.w));
      *(unsigned long long*)(xbr + h0) = (unsigned long long)lo | ((unsigned long long)hi << 32);
      float xs[4] = {xv.x, xv.y, xv.z, xv.w};
#pragma unroll
      for (int j = 0; j < 4; ++j) {
        const float4* g4 = (const float4*)(gw + (size_t)(h0 + j) * EXP);
        float4 glo = g4[0], ghi = g4[1];
        acc[0] += xs[j] * glo.x; acc[1] += xs[j] * glo.y;
        acc[2] += xs[j] * glo.z; acc[3] += xs[j] * glo.w;
        acc[4] += xs[j] * ghi.x; acc[5] += xs[j] * ghi.y;
        acc[6] += xs[j] * ghi.z; acc[7] += xs[j] * ghi.w;
      }
    }
#pragma unroll
    for (int off = 32; off > 0; off >>= 1) {
#pragma unroll
      for (int i = 0; i < 8; ++i) acc[i] += __shfl_xor(acc[i], off, 64);
    }
    if (lane == 0) {
#pragma unroll
      for (int i = 0; i < 8; ++i) logitsT[(size_t)i * T_TOK + t] = acc[i];
    }
    return;
  }
  // ---------------- transpose path
  int b = bb;
  const float* in; ushort_t* out; int R, Cc;
  if (b < 4096)      { in = w1; out = w1t; R = HDIM; Cc = FDIM; }
  else if (b < 8192) { in = w3; out = w3t; R = HDIM; Cc = FDIM; b -= 4096; }
  else               { in = w2; out = w2t; R = FDIM; Cc = HDIM; b -= 8192; }
  int tilesC = Cc >> 6;
  int tilesPer = (R >> 6) * tilesC;
  int e = b / tilesPer;
  int tb = b - e * tilesPer;
  int rt = tb / tilesC, ct = tb - rt * tilesC;
  const float* src = in + (size_t)e * R * Cc;
  ushort_t* dst = out + (size_t)e * R * Cc;
  int tr = threadIdx.x >> 4, tc = threadIdx.x & 15;
#pragma unroll
  for (int it = 0; it < 4; ++it) {
    int r = (rt << 6) + (it << 4) + tr;
    int c = (ct << 6) + (tc << 2);
    float4 v = *(const float4*)(src + (size_t)r * Cc + c);
    tile[(it << 4) + tr][(tc << 2) + 0] = v.x;
    tile[(it << 4) + tr][(tc << 2) + 1] = v.y;
    tile[(it << 4) + tr][(tc << 2) + 2] = v.z;
    tile[(it << 4) + tr][(tc << 2) + 3] = v.w;
  }
  __syncthreads();
#pragma unroll
  for (int it = 0; it < 4; ++it) {
    int cl = (it << 4) + tr;
    int rl = tc << 2;
    unsigned lo = pk2(f2b(tile[rl + 0][cl]), f2b(tile[rl + 1][cl]));
    unsigned hi = pk2(f2b(tile[rl + 2][cl]), f2b(tile[rl + 3][cl]));
    unsigned long long v = (unsigned long long)lo | ((unsigned long long)hi << 32);
    *(unsigned long long*)(dst + (size_t)((ct << 6) + cl) * R + (rt << 6) + rl) = v;
  }
}

// ------------------------------- radix-select: exact CAP-th largest per expert
__global__ void __launch_bounds__(256) select_k(
    const float* __restrict__ logitsT,
    unsigned* __restrict__ thr, int* __restrict__ needo, unsigned* __restrict__ umax)
{
  __shared__ int hist[4][256];
  __shared__ int ssum[256];
  __shared__ unsigned s_pref;
  __shared__ int s_rem;
  __shared__ unsigned smx[4];
  int e = blockIdx.x, tid = threadIdx.x;
  const float* base = logitsT + (size_t)e * T_TOK;

  unsigned m[32];
  unsigned mmax = 0;
#pragma unroll
  for (int i = 0; i < 32; ++i) {
    m[i] = map_u(base[tid + i * 256]);
    mmax = m[i] > mmax ? m[i] : mmax;
  }
#pragma unroll
  for (int off = 32; off > 0; off >>= 1) {
    unsigned o = __shfl_xor(mmax, off, 64);
    mmax = o > mmax ? o : mmax;
  }
  int lane = tid & 63, wv = tid >> 6;
  if (lane == 0) smx[wv] = mmax;
  if (tid == 0) { s_pref = 0; s_rem = CAP; }
  __syncthreads();
  if (tid == 0) {
    unsigned a = smx[0] > smx[1] ? smx[0] : smx[1];
    unsigned b = smx[2] > smx[3] ? smx[2] : smx[3];
    umax[e] = a > b ? a : b;
  }

  for (int r = 0; r < 4; ++r) {
#pragma unroll
    for (int w = 0; w < 4; ++w) hist[w][tid] = 0;
    __syncthreads();
    unsigned pref = s_pref;
    int rem = s_rem;
    int shift = 24 - 8 * r;
#pragma unroll
    for (int i = 0; i < 32; ++i) {
      unsigned u = m[i];
      bool ok = (r == 0) || ((u >> (shift + 8)) == (pref >> (shift + 8)));
      if (ok) atomicAdd(&hist[wv][(u >> shift) & 255], 1);
    }
    __syncthreads();
    ssum[tid] = hist[0][tid] + hist[1][tid] + hist[2][tid] + hist[3][tid];
    __syncthreads();
    for (int st = 1; st < 256; st <<= 1) {
      int add = (tid + st < 256) ? ssum[tid + st] : 0;
      __syncthreads();
      ssum[tid] += add;
      __syncthreads();
    }
    int above = (tid < 255) ? ssum[tid + 1] : 0;   // count strictly above bin tid
    if (ssum[tid] >= rem && above < rem) {
      s_pref = pref | ((unsigned)tid << shift);
      s_rem = rem - above;
    }
    __syncthreads();
  }
  if (tid == 0) { thr[e] = s_pref; needo[e] = s_rem; }
}

// ------------------------- emit: threshold test + slot assign + token lists
__global__ void __launch_bounds__(256) emit_k(
    const float* __restrict__ logitsT,
    const unsigned* __restrict__ thr, const int* __restrict__ needv,
    const unsigned* __restrict__ umaxv,
    int* __restrict__ idxo, float* __restrict__ exo,
    int* __restrict__ cnt, int* __restrict__ tie, float* __restrict__ expsum,
    int* __restrict__ tok_cnt, int* __restrict__ tok_ent)
{
  int t = blockIdx.x * 256 + threadIdx.x;
  int lane = threadIdx.x & 63;
  int lc = 0;
  int ents[8];
#pragma unroll
  for (int e = 0; e < EXP; ++e) {
    float f = logitsT[(size_t)e * T_TOK + t];
    unsigned u = map_u(f);
    unsigned te = thr[e];
    float fm = unmap_f(umaxv[e]);
    float v = __expf(f - fm);
    bool sel = u > te;
    unsigned long long mask = __ballot(sel);
    int nsel = __popcll(mask);
    int base = 0;
    if (lane == 0 && nsel) base = atomicAdd(&cnt[e], nsel);
    base = __shfl(base, 0, 64);
    int slot = -1;
    if (sel) slot = base + __popcll(mask & ((1ull << lane) - 1ull));
    // rare tie path (== threshold): admit exactly needv[e]
    if (u == te) {
      int k = atomicAdd(&tie[e], 1);
      if (k < needv[e]) {
        slot = atomicAdd(&cnt[e], 1);
        atomicAdd(&expsum[e], v);
      }
    }
    if (slot >= 0) {
      idxo[e * CAP + slot] = t;
      exo[e * CAP + slot] = v;
      ents[lc++] = (e << 16) | slot;
    }
    float vs = sel ? v : 0.f;
#pragma unroll
    for (int off = 32; off > 0; off >>= 1) vs += __shfl_xor(vs, off, 64);
    if (lane == 0 && vs != 0.f) atomicAdd(&expsum[e], vs);
  }
  tok_cnt[t] = lc;
  for (int i = 0; i < lc; ++i) tok_ent[t * 8 + i] = ents[i];
}

// ------------------------------------------------- GEMM1: SwiGLU hidden (bf16 MFMA)
// 128(tok) x 64(f, dual w1/w3) tile, BK=32, 256 thr (4 waves = 2M x 2N).
// Ring-3 (48 KB LDS -> 3 blocks/CU target), 2-tile-ahead prefetch, counted
// s_waitcnt vmcnt(4) + raw s_barrier. Grid 2560: e=XCD, ft-outer/mt-inner so
// the B-panel is shared by 10 consecutive blocks and A set stays L2-resident.
#define G1_STAGE(BB) \
  gl_lds16(pA0, lds + (BB)*8192 + (size_t)tid*8); \
  gl_lds16(pA1, lds + (BB)*8192 + 2048 + (size_t)tid*8); \
  gl_lds16(pB0, lds + (BB)*8192 + 4096 + (size_t)tid*8); \
  gl_lds16(pB1, lds + (BB)*8192 + 6144 + (size_t)tid*8);

#define G1_ADV { pA0 += 32; pA1 += 32; pB0 += 32; pB1 += 32; }

#define G1_ITER(CB, VM, PREF) { \
  asm volatile("s_waitcnt vmcnt(" VM ")" ::: "memory"); \
  __builtin_amdgcn_s_barrier(); \
  if (PREF) { G1_STAGE(((CB) + 2) % 3); G1_ADV; } \
  bf16x8 af[4], b1v[2], b3v[2]; \
  _Pragma("unroll") \
  for (int mi = 0; mi < 4; ++mi) af[mi] = *(const bf16x8*)(lds + (CB)*8192 + aoff[mi]); \
  _Pragma("unroll") \
  for (int nj = 0; nj < 2; ++nj) { \
    b1v[nj] = *(const bf16x8*)(lds + (CB)*8192 + b1off[nj]); \
    b3v[nj] = *(const bf16x8*)(lds + (CB)*8192 + b1off[nj] + 2048); } \
  __builtin_amdgcn_s_setprio(1); \
  _Pragma("unroll") \
  for (int mi = 0; mi < 4; ++mi) \
    _Pragma("unroll") \
    for (int nj = 0; nj < 2; ++nj) { \
      acc1[mi][nj] = __builtin_amdgcn_mfma_f32_16x16x32_bf16(af[mi], b1v[nj], acc1[mi][nj], 0, 0, 0); \
      acc3[mi][nj] = __builtin_amdgcn_mfma_f32_16x16x32_bf16(af[mi], b3v[nj], acc3[mi][nj], 0, 0, 0); } \
  __builtin_amdgcn_s_setprio(0); \
}

__global__ void __launch_bounds__(256) gemm1_swiglu_k(
    const ushort_t* __restrict__ xb,   // [T_TOK][HDIM]
    const ushort_t* __restrict__ w1t,  // [E][FDIM][HDIM]
    const ushort_t* __restrict__ w3t,
    const int* __restrict__ idx,       // [E][CAP]
    ushort_t* __restrict__ hidden)     // [E][CAP][FDIM]
{
  int bb = blockIdx.x;
  int e = bb & 7;                      // expert = XCD
  int k = bb >> 3;                     // 0..319 within XCD
  int mt = k % 10;                     // token-tile (inner: 10 share a B-panel)
  int ft = k / 10;                     // 0..31 f-panel
  int f0 = ft * 64;

  // 3 ring buffers x (A 128x32 | B 128x32) x 2B = 48 KB
  __shared__ __bf16 lds[3 * 8192];

  int tid = threadIdx.x;
  int lane = tid & 63, wave = tid >> 6;
  int wm = wave >> 1;                 // 0..1 : token-row group of 64
  int wn = wave & 1;                  // 0..1 : f-col group of 32
  int l15 = lane & 15, quad = lane >> 4;

  // -------- staging: r = row 0..63 (and +64), c = 16B chunk 0..3
  int r = tid >> 2;
  int c = tid & 3;
  int s_sw = (r & 3) ^ ((r >> 2) & 3);     // same for r and r+64
  int g_chunk = ((c ^ s_sw) * 8);          // pre-swizzled global elem offset

  const int* idxe = idx + e * CAP + mt * 128;
  int tok0 = idxe[r];
  int tok1 = idxe[r + 64];
  const ushort_t* pA0 = xb + (size_t)tok0 * HDIM + g_chunk;
  const ushort_t* pA1 = xb + (size_t)tok1 * HDIM + g_chunk;
  const ushort_t* pB0 = w1t + ((size_t)e * FDIM + f0 + r) * HDIM + g_chunk;
  const ushort_t* pB1 = w3t + ((size_t)e * FDIM + f0 + r) * HDIM + g_chunk;

  // -------- ds_read fragment offsets (bf16 elems, buffer-relative)
  int aoff[4], b1off[2];
#pragma unroll
  for (int mi = 0; mi < 4; ++mi) {
    int R = wm * 64 + mi * 16 + l15;       // 0..127
    int sw = (R & 3) ^ ((R >> 2) & 3);
    aoff[mi] = R * 32 + ((quad ^ sw) * 8);
  }
#pragma unroll
  for (int nj = 0; nj < 2; ++nj) {
    int r1 = wn * 32 + nj * 16 + l15;      // 0..63 (w1 rows; w3 at +2048 elems)
    int sw = (r1 & 3) ^ ((r1 >> 2) & 3);
    b1off[nj] = 4096 + r1 * 32 + ((quad ^ sw) * 8);
  }

  f32x4 acc1[4][2], acc3[4][2];
#pragma unroll
  for (int i = 0; i < 4; ++i)
#pragma unroll
    for (int j = 0; j < 2; ++j) {
      acc1[i][j] = (f32x4){0.f, 0.f, 0.f, 0.f};
      acc3[i][j] = (f32x4){0.f, 0.f, 0.f, 0.f};
    }

  // -------- prologue: stage K-tiles 0,1 ; pointers end at K-tile 2
  G1_STAGE(0); G1_ADV;
  G1_STAGE(1); G1_ADV;

  // -------- main loop: 32 K-tiles; iter t consumes buf[t%3], prefetches t+2
  for (int it = 0; it < 10; ++it) {
    G1_ITER(0, "4", 1)
    G1_ITER(1, "4", 1)
    G1_ITER(2, "4", 1)
  }
  G1_ITER(0, "4", 0)   // t=30
  G1_ITER(1, "0", 0)   // t=31 (final: drain)

  // -------- epilogue: silu(a)*g, lane-local; C/D: col=l15, row=quad*4+reg
  ushort_t* hb = hidden + ((size_t)e * CAP + mt * 128) * FDIM + f0;
#pragma unroll
  for (int mi = 0; mi < 4; ++mi)
#pragma unroll
    for (int nj = 0; nj < 2; ++nj)
#pragma unroll
      for (int rr = 0; rr < 4; ++rr) {
        int row = wm * 64 + mi * 16 + quad * 4 + rr;
        int col = wn * 32 + nj * 16 + l15;
        float v1 = acc1[mi][nj][rr];
        float v3 = acc3[mi][nj][rr];
        float s = (v1 / (1.f + __expf(-v1))) * v3;
        hb[(size_t)row * FDIM + col] = f2b(s);
      }
}

// ------------------------------------- GEMM2: hidden @ w2 -> weighted store (no atomics)
// Ring-3 counted-vmcnt: 128x128 tile, BK=32, 512 thr (8 waves = 2M x 4N),
// 48 KB LDS. vmcnt(2) steady state. XCD swizzle (640 = 8x80).
#define G2_STAGE(BB) \
  gl_lds16(pA, lds2 + (BB)*8192 + (size_t)tid*8); \
  gl_lds16(pB, lds2 + (BB)*8192 + 4096 + (size_t)tid*8);

#define G2_ITER(CB, PB, VM, PREF) { \
  asm volatile("s_waitcnt vmcnt(" VM ")" ::: "memory"); \
  __builtin_amdgcn_s_barrier(); \
  if (PREF) { G2_STAGE(PB); pA += 32; pB += 32; } \
  bf16x8 af[4], bf[2]; \
  _Pragma("unroll") \
  for (int mi = 0; mi < 4; ++mi) af[mi] = *(const bf16x8*)(lds2 + (CB)*8192 + aoff[mi]); \
  _Pragma("unroll") \
  for (int nj = 0; nj < 2; ++nj) bf[nj] = *(const bf16x8*)(lds2 + (CB)*8192 + boff[nj]); \
  __builtin_amdgcn_s_setprio(1); \
  _Pragma("unroll") \
  for (int mi = 0; mi < 4; ++mi) \
    _Pragma("unroll") \
    for (int nj = 0; nj < 2; ++nj) \
      acc[mi][nj] = __builtin_amdgcn_mfma_f32_16x16x32_bf16(af[mi], bf[nj], acc[mi][nj], 0, 0, 0); \
  __builtin_amdgcn_s_setprio(0); \
}

__global__ void __launch_bounds__(512) gemm2_k(
    const ushort_t* __restrict__ hidden, // [E][CAP][FDIM]
    const ushort_t* __restrict__ w2t,    // [E][HDIM][FDIM]
    const float* __restrict__ ex, const float* __restrict__ expsum,
    float* __restrict__ oute)            // [E][CAP][HDIM] fp32, weighted
{
  int bb = blockIdx.x;
  int b = (bb & 7) * 80 + (bb >> 3);    // XCD-bijective swizzle (nwg=640)
  int nt = b & 7; int t1 = b >> 3; int mt = t1 % 10; int e = t1 / 10;

  // 3 ring buffers x (A 128x32 = 4096 el | B 128x32 = 4096 el) = 48 KB
  __shared__ __bf16 lds2[3 * 8192];
  __shared__ float wgts[128];

  int tid = threadIdx.x;
  int lane = tid & 63, wave = tid >> 6;
  int wm = wave >> 2;                 // 0..1 : hidden-slot group of 64
  int wn = wave & 3;                  // 0..3 : h-col group of 32
  int l15 = lane & 15, quad = lane >> 4;

  if (tid < 128) wgts[tid] = ex[e * CAP + mt * 128 + tid] / expsum[e];

  // -------- staging: srow 0..127, chunk 0..3 (16B each)
  int srow = tid >> 2;
  int chunk = tid & 3;
  int s_sw = (srow & 3) ^ ((srow >> 2) & 3);
  int g_chunk = ((chunk ^ s_sw) * 8);

  const ushort_t* pA = hidden + ((size_t)e * CAP + mt * 128 + srow) * FDIM + g_chunk;
  const ushort_t* pB = w2t + ((size_t)e * HDIM + nt * 128 + srow) * FDIM + g_chunk;

  // -------- ds_read fragment offsets (bf16 elems, buffer-relative)
  int aoff[4], boff[2];
#pragma unroll
  for (int mi = 0; mi < 4; ++mi) {
    int R = wm * 64 + mi * 16 + l15;
    int sw = (R & 3) ^ ((R >> 2) & 3);
    aoff[mi] = R * 32 + ((quad ^ sw) * 8);
  }
#pragma unroll
  for (int nj = 0; nj < 2; ++nj) {
    int r2 = wn * 32 + nj * 16 + l15;
    int sw = (r2 & 3) ^ ((r2 >> 2) & 3);
    boff[nj] = 4096 + r2 * 32 + ((quad ^ sw) * 8);
  }

  f32x4 acc[4][2];
#pragma unroll
  for (int i = 0; i < 4; ++i)
#pragma unroll
    for (int j = 0; j < 2; ++j) acc[i][j] = (f32x4){0.f, 0.f, 0.f, 0.f};

  // -------- prologue: stage K-tiles 0,1
  G2_STAGE(0); pA += 32; pB += 32;
  G2_STAGE(1); pA += 32; pB += 32;

  // -------- main loop: 64 K-tiles (FDIM/32)
  for (int it = 0; it < 20; ++it) {
    G2_ITER(0, 2, "2", 1)
    G2_ITER(1, 0, "2", 1)
    G2_ITER(2, 1, "2", 1)
  }
  G2_ITER(0, 2, "2", 1)   // t=60, pref t62
  G2_ITER(1, 0, "2", 1)   // t=61, pref t63
  G2_ITER(2, 0, "2", 0)   // t=62
  G2_ITER(0, 0, "0", 0)   // t=63 (final: drain)

  float* ob = oute + ((size_t)e * CAP + mt * 128) * HDIM + nt * 128;
#pragma unroll
  for (int mi = 0; mi < 4; ++mi)
#pragma unroll
    for (int nj = 0; nj < 2; ++nj)
#pragma unroll
      for (int rr = 0; rr < 4; ++rr) {
        int row = wm * 64 + mi * 16 + quad * 4 + rr;
        int col = wn * 32 + nj * 16 + l15;
        ob[(size_t)row * HDIM + col] = acc[mi][nj][rr] * wgts[row];
      }
}

// ---------------------------------------- combine: per-token gather-sum -> y
__global__ void __launch_bounds__(256) combine_k(
    const float* __restrict__ oute,      // [E][CAP][HDIM] weighted
    const int* __restrict__ tok_cnt, const int* __restrict__ tok_ent,
    float* __restrict__ y)               // [T_TOK][HDIM]
{
  int t = blockIdx.x;
  int c = threadIdx.x * 4;
  int n = tok_cnt[t];
  float4 acc = {0.f, 0.f, 0.f, 0.f};
  for (int i = 0; i < n; ++i) {
    int ent = tok_ent[t * 8 + i];
    int e = ent >> 16, slot = ent & 0xffff;
    float4 v = *(const float4*)(oute + (((size_t)e * CAP + slot) << 10) + c);
    acc.x += v.x; acc.y += v.y; acc.z += v.z; acc.w += v.w;
  }
  *(float4*)(y + ((size_t)t << 10) + c) = acc;
}

// --------------------------------------------------------------------- launch
extern "C" void kernel_launch(void* const* d_in, const int* in_sizes, int n_in,
                              void* d_out, int out_size, void* d_ws, size_t ws_size,
                              hipStream_t stream)
{
  const float* x  = (const float*)d_in[0];
  const float* gw = (const float*)d_in[1];
  const float* w1 = (const float*)d_in[2];
  const float* w2 = (const float*)d_in[3];
  const float* w3 = (const float*)d_in[4];
  float* y = (float*)d_out;

  char* ws = (char*)d_ws;
  float*    logitsT = (float*)(ws + 0x0);          // 256 KB [E][T]
  int*      idx     = (int*)(ws + 0x40000);        // 40 KB
  float*    exo     = (float*)(ws + 0x4A000);      // 40 KB
  unsigned* thr    = (unsigned*)(ws + 0x54000);    // ctrl block (zeroed): 256 B
  int*      need   = (int*)(ws + 0x54020);
  unsigned* umax   = (unsigned*)(ws + 0x54040);
  int*      cnt    = (int*)(ws + 0x54060);
  int*      tie    = (int*)(ws + 0x54080);
  float*    expsum = (float*)(ws + 0x540A0);
  int*      tok_cnt = (int*)(ws + 0x55000);        // 32 KB
  int*      tok_ent = (int*)(ws + 0x5D000);        // 256 KB
  ushort_t* xb     = (ushort_t*)(ws + 0xA0000);    // 16 MB  [T][H] bf16
  ushort_t* w1t    = (ushort_t*)(ws + 0x10A0000);  // 32 MB  [E][F][H]
  ushort_t* w3t    = (ushort_t*)(ws + 0x30A0000);  // 32 MB
  ushort_t* w2t    = (ushort_t*)(ws + 0x50A0000);  // 32 MB  [E][H][F]
  ushort_t* hid    = (ushort_t*)(ws + 0x70A0000);  // 40 MB  [E][CAP][F]
  float*    oute   = (float*)(ws + 0x10A0000);     // 40 MB, aliases w1t+w3t (dead after gemm1)

  // tail of d_out beyond y (the scalar 0.0 output) must be zero
  size_t yelems = (size_t)T_TOK * HDIM;
  if ((size_t)out_size > yelems)
    hipMemsetAsync((char*)d_out + yelems * 4, 0, ((size_t)out_size - yelems) * 4, stream);
  hipMemsetAsync(ws + 0x54000, 0, 256, stream);

  prep_k<<<12288 + 2048, 256, 0, stream>>>(w1, w3, w2, w1t, w3t, w2t, x, gw, logitsT, xb);
  select_k<<<EXP, 256, 0, stream>>>(logitsT, thr, need, umax);
  emit_k<<<T_TOK / 256, 256, 0, stream>>>(logitsT, thr, need, umax, idx, exo, cnt, tie, expsum, tok_cnt, tok_ent);
  gemm1_swiglu_k<<<EXP * 10 * 32, 256, 0, stream>>>(xb, w1t, w3t, idx, hid);
  gemm2_k<<<EXP * 10 * 8, 512, 0, stream>>>(hid, w2t, exo, expsum, oute);
  combine_k<<<T_TOK, 256, 0, stream>>>(oute, tok_cnt, tok_ent, y);
}

// Round 6
// 465.930 us; speedup vs baseline: 1.0205x; 1.0205x over previous
//
#include <hip/hip_runtime.h>
#include <stdint.h>

typedef unsigned short ushort_t;
typedef __bf16 bf16x8 __attribute__((ext_vector_type(8)));
typedef float f32x4 __attribute__((ext_vector_type(4)));

#define T_TOK 8192
#define HDIM  1024
#define EXP   8
#define FDIM  2048
#define CAP   1280

// fp32 -> bf16 round-to-nearest-even
__device__ __forceinline__ unsigned short f2b(float f) {
  unsigned u = __float_as_uint(f);
  u = (u + 0x7fffu + ((u >> 16) & 1u)) >> 16;
  return (unsigned short)u;
}
__device__ __forceinline__ unsigned pk2(unsigned short lo, unsigned short hi) {
  return (unsigned)lo | ((unsigned)hi << 16);
}
// order-preserving fp32 -> u32 map (monotone increasing)
__device__ __forceinline__ unsigned map_u(float f) {
  unsigned u = __float_as_uint(f);
  return (u & 0x80000000u) ? ~u : (u | 0x80000000u);
}
__device__ __forceinline__ float unmap_f(unsigned m) {
  unsigned u = (m & 0x80000000u) ? (m ^ 0x80000000u) : ~m;
  return __uint_as_float(u);
}
// async global->LDS, 16B/lane; LDS dest = wave-uniform base + lane*16
__device__ __forceinline__ void gl_lds16(const void* g, void* l) {
  __builtin_amdgcn_global_load_lds((__attribute__((address_space(1))) void*)g,
                                   (__attribute__((address_space(3))) void*)l,
                                   16, 0, 0);
}

// --------------- prep: fused weight transpose+cast (w1,w3,w2) AND gating GEMV
// Transpose blocks [0,3072): each handles FOUR 64x64 tiles of one row-strip,
// with ALL 16 float4 global loads issued up-front (latency overlap), then four
// LDS write->transposed bf16-store phases. Gate blocks [3072,5120).
#define PREP_LOAD(VV, G) { \
  _Pragma("unroll") \
  for (int it = 0; it < 4; ++it) { \
    int r = (rt << 6) + (it << 4) + tr; \
    int c = ((ct0 + (G)) << 6) + (tc << 2); \
    VV[it] = *(const float4*)(src + (size_t)r * Cc + c); \
  } }

#define PREP_DO(VV, G) { \
  __syncthreads(); \
  _Pragma("unroll") \
  for (int it = 0; it < 4; ++it) { \
    tile[(it << 4) + tr][(tc << 2) + 0] = VV[it].x; \
    tile[(it << 4) + tr][(tc << 2) + 1] = VV[it].y; \
    tile[(it << 4) + tr][(tc << 2) + 2] = VV[it].z; \
    tile[(it << 4) + tr][(tc << 2) + 3] = VV[it].w; \
  } \
  __syncthreads(); \
  _Pragma("unroll") \
  for (int it = 0; it < 4; ++it) { \
    int cl = (it << 4) + tr; \
    int rl = tc << 2; \
    unsigned lo = pk2(f2b(tile[rl + 0][cl]), f2b(tile[rl + 1][cl])); \
    unsigned hi = pk2(f2b(tile[rl + 2][cl]), f2b(tile[rl + 3][cl])); \
    unsigned long long v = (unsigned long long)lo | ((unsigned long long)hi << 32); \
    *(unsigned long long*)(dst + (size_t)(((ct0 + (G)) << 6) + cl) * R + (rt << 6) + rl) = v; \
  } }

__global__ void __launch_bounds__(256) prep_k(
    const float* __restrict__ w1, const float* __restrict__ w3, const float* __restrict__ w2,
    ushort_t* __restrict__ w1t, ushort_t* __restrict__ w3t, ushort_t* __restrict__ w2t,
    const float* __restrict__ x, const float* __restrict__ gw,
    float* __restrict__ logitsT, ushort_t* __restrict__ xb)
{
  __shared__ float tile[64][65];
  int bb = blockIdx.x;
  if (bb >= 3072) {
    // ---------------- gate + cast path
    int wave = threadIdx.x >> 6, lane = threadIdx.x & 63;
    int t = (bb - 3072) * 4 + wave;
    const float* xr = x + (size_t)t * HDIM;
    ushort_t* xbr = xb + (size_t)t * HDIM;
    float acc[8];
#pragma unroll
    for (int i = 0; i < 8; ++i) acc[i] = 0.f;
#pragma unroll
    for (int i = 0; i < 4; ++i) {
      int h0 = i * 256 + lane * 4;
      float4 xv = *(const float4*)(xr + h0);
      unsigned lo = pk2(f2b(xv.x), f2b(xv.y));
      unsigned hi = pk2(f2b(xv.z), f2b(xv.w));
      *(unsigned long long*)(xbr + h0) = (unsigned long long)lo | ((unsigned long long)hi << 32);
      float xs[4] = {xv.x, xv.y, xv.z, xv.w};
#pragma unroll
      for (int j = 0; j < 4; ++j) {
        const float4* g4 = (const float4*)(gw + (size_t)(h0 + j) * EXP);
        float4 glo = g4[0], ghi = g4[1];
        acc[0] += xs[j] * glo.x; acc[1] += xs[j] * glo.y;
        acc[2] += xs[j] * glo.z; acc[3] += xs[j] * glo.w;
        acc[4] += xs[j] * ghi.x; acc[5] += xs[j] * ghi.y;
        acc[6] += xs[j] * ghi.z; acc[7] += xs[j] * ghi.w;
      }
    }
#pragma unroll
    for (int off = 32; off > 0; off >>= 1) {
#pragma unroll
      for (int i = 0; i < 8; ++i) acc[i] += __shfl_xor(acc[i], off, 64);
    }
    if (lane == 0) {
#pragma unroll
      for (int i = 0; i < 8; ++i) logitsT[(size_t)i * T_TOK + t] = acc[i];
    }
    return;
  }
  // ---------------- transpose path: 1024 blocks per matrix, 4 tiles per block
  int b = bb;
  const float* in; ushort_t* out; int R, Cc;
  if (b < 1024)      { in = w1; out = w1t; R = HDIM; Cc = FDIM; }
  else if (b < 2048) { in = w3; out = w3t; R = HDIM; Cc = FDIM; b -= 1024; }
  else               { in = w2; out = w2t; R = FDIM; Cc = HDIM; b -= 2048; }
  int colgroups = Cc >> 8;                 // groups of 4 column-tiles
  int e = b >> 7;                          // 128 blocks per expert
  int tb = b & 127;
  int rt = tb / colgroups;
  int ct0 = (tb % colgroups) * 4;
  const float* src = in + (size_t)e * R * Cc;
  ushort_t* dst = out + (size_t)e * R * Cc;
  int tr = threadIdx.x >> 4, tc = threadIdx.x & 15;

  float4 v0[4], v1[4], v2[4], v3[4];
  PREP_LOAD(v0, 0)
  PREP_LOAD(v1, 1)
  PREP_LOAD(v2, 2)
  PREP_LOAD(v3, 3)
  PREP_DO(v0, 0)
  PREP_DO(v1, 1)
  PREP_DO(v2, 2)
  PREP_DO(v3, 3)
}

// ------------------------------- radix-select: exact CAP-th largest per expert
__global__ void __launch_bounds__(256) select_k(
    const float* __restrict__ logitsT,
    unsigned* __restrict__ thr, int* __restrict__ needo, unsigned* __restrict__ umax)
{
  __shared__ int hist[4][256];
  __shared__ int ssum[256];
  __shared__ unsigned s_pref;
  __shared__ int s_rem;
  __shared__ unsigned smx[4];
  int e = blockIdx.x, tid = threadIdx.x;
  const float* base = logitsT + (size_t)e * T_TOK;

  unsigned m[32];
  unsigned mmax = 0;
#pragma unroll
  for (int i = 0; i < 32; ++i) {
    m[i] = map_u(base[tid + i * 256]);
    mmax = m[i] > mmax ? m[i] : mmax;
  }
#pragma unroll
  for (int off = 32; off > 0; off >>= 1) {
    unsigned o = __shfl_xor(mmax, off, 64);
    mmax = o > mmax ? o : mmax;
  }
  int lane = tid & 63, wv = tid >> 6;
  if (lane == 0) smx[wv] = mmax;
  if (tid == 0) { s_pref = 0; s_rem = CAP; }
  __syncthreads();
  if (tid == 0) {
    unsigned a = smx[0] > smx[1] ? smx[0] : smx[1];
    unsigned b = smx[2] > smx[3] ? smx[2] : smx[3];
    umax[e] = a > b ? a : b;
  }

  for (int r = 0; r < 4; ++r) {
#pragma unroll
    for (int w = 0; w < 4; ++w) hist[w][tid] = 0;
    __syncthreads();
    unsigned pref = s_pref;
    int rem = s_rem;
    int shift = 24 - 8 * r;
#pragma unroll
    for (int i = 0; i < 32; ++i) {
      unsigned u = m[i];
      bool ok = (r == 0) || ((u >> (shift + 8)) == (pref >> (shift + 8)));
      if (ok) atomicAdd(&hist[wv][(u >> shift) & 255], 1);
    }
    __syncthreads();
    ssum[tid] = hist[0][tid] + hist[1][tid] + hist[2][tid] + hist[3][tid];
    __syncthreads();
    for (int st = 1; st < 256; st <<= 1) {
      int add = (tid + st < 256) ? ssum[tid + st] : 0;
      __syncthreads();
      ssum[tid] += add;
      __syncthreads();
    }
    int above = (tid < 255) ? ssum[tid + 1] : 0;   // count strictly above bin tid
    if (ssum[tid] >= rem && above < rem) {
      s_pref = pref | ((unsigned)tid << shift);
      s_rem = rem - above;
    }
    __syncthreads();
  }
  if (tid == 0) { thr[e] = s_pref; needo[e] = s_rem; }
}

// ------------------------- emit: threshold test + slot assign + token lists
__global__ void __launch_bounds__(256) emit_k(
    const float* __restrict__ logitsT,
    const unsigned* __restrict__ thr, const int* __restrict__ needv,
    const unsigned* __restrict__ umaxv,
    int* __restrict__ idxo, float* __restrict__ exo,
    int* __restrict__ cnt, int* __restrict__ tie, float* __restrict__ expsum,
    int* __restrict__ tok_cnt, int* __restrict__ tok_ent)
{
  int t = blockIdx.x * 256 + threadIdx.x;
  int lane = threadIdx.x & 63;
  int lc = 0;
  int ents[8];
#pragma unroll
  for (int e = 0; e < EXP; ++e) {
    float f = logitsT[(size_t)e * T_TOK + t];
    unsigned u = map_u(f);
    unsigned te = thr[e];
    float fm = unmap_f(umaxv[e]);
    float v = __expf(f - fm);
    bool sel = u > te;
    unsigned long long mask = __ballot(sel);
    int nsel = __popcll(mask);
    int base = 0;
    if (lane == 0 && nsel) base = atomicAdd(&cnt[e], nsel);
    base = __shfl(base, 0, 64);
    int slot = -1;
    if (sel) slot = base + __popcll(mask & ((1ull << lane) - 1ull));
    // rare tie path (== threshold): admit exactly needv[e]
    if (u == te) {
      int k = atomicAdd(&tie[e], 1);
      if (k < needv[e]) {
        slot = atomicAdd(&cnt[e], 1);
        atomicAdd(&expsum[e], v);
      }
    }
    if (slot >= 0) {
      idxo[e * CAP + slot] = t;
      exo[e * CAP + slot] = v;
      ents[lc++] = (e << 16) | slot;
    }
    float vs = sel ? v : 0.f;
#pragma unroll
    for (int off = 32; off > 0; off >>= 1) vs += __shfl_xor(vs, off, 64);
    if (lane == 0 && vs != 0.f) atomicAdd(&expsum[e], vs);
  }
  tok_cnt[t] = lc;
  for (int i = 0; i < lc; ++i) tok_ent[t * 8 + i] = ents[i];
}

// ------------------------------------------------- GEMM1: SwiGLU hidden (bf16 MFMA)
// R4-proven config: 256(tok) x 64(f, dual w1/w3) tile, BK=32, 512 thr (8 waves
// = 4M x 2N). 3-buffer ring, 2-tile-ahead prefetch, counted s_waitcnt vmcnt(3)
// + raw s_barrier. XCD-bijective grid swizzle (1280 = 8x160).
#define G1_STAGE(BB) \
  gl_lds16(pA0, lds + (BB)*12288 + (size_t)tid*8); \
  gl_lds16(pA1, lds + (BB)*12288 + 4096 + (size_t)tid*8); \
  gl_lds16(pB , lds + (BB)*12288 + 8192 + (size_t)tid*8);

#define G1_ITER(CB, PB, VM, PREF) { \
  asm volatile("s_waitcnt vmcnt(" VM ")" ::: "memory"); \
  __builtin_amdgcn_s_barrier(); \
  if (PREF) { G1_STAGE(PB); pA0 += 32; pA1 += 32; pB += 32; } \
  bf16x8 af[4], b1v[2], b3v[2]; \
  _Pragma("unroll") \
  for (int mi = 0; mi < 4; ++mi) af[mi] = *(const bf16x8*)(lds + (CB)*12288 + aoff[mi]); \
  _Pragma("unroll") \
  for (int nj = 0; nj < 2; ++nj) { \
    b1v[nj] = *(const bf16x8*)(lds + (CB)*12288 + b1off[nj]); \
    b3v[nj] = *(const bf16x8*)(lds + (CB)*12288 + b1off[nj] + 2048); } \
  __builtin_amdgcn_s_setprio(1); \
  _Pragma("unroll") \
  for (int mi = 0; mi < 4; ++mi) \
    _Pragma("unroll") \
    for (int nj = 0; nj < 2; ++nj) { \
      acc1[mi][nj] = __builtin_amdgcn_mfma_f32_16x16x32_bf16(af[mi], b1v[nj], acc1[mi][nj], 0, 0, 0); \
      acc3[mi][nj] = __builtin_amdgcn_mfma_f32_16x16x32_bf16(af[mi], b3v[nj], acc3[mi][nj], 0, 0, 0); } \
  __builtin_amdgcn_s_setprio(0); \
}

__global__ void __launch_bounds__(512) gemm1_swiglu_k(
    const ushort_t* __restrict__ xb,   // [T_TOK][HDIM]
    const ushort_t* __restrict__ w1t,  // [E][FDIM][HDIM]
    const ushort_t* __restrict__ w3t,
    const int* __restrict__ idx,       // [E][CAP]
    ushort_t* __restrict__ hidden)     // [E][CAP][FDIM]
{
  int bb = blockIdx.x;
  int b = (bb & 7) * 160 + (bb >> 3);   // XCD-bijective swizzle (nwg=1280)
  int ft = b & 31; int t1 = b >> 5; int mt = t1 % 5; int e = t1 / 5;
  int f0 = ft * 64;

  // 3 ring buffers x (A 256x32 = 8192 el | B 128x32 = 4096 el) = 72 KB
  __shared__ __bf16 lds[3 * 12288];

  int tid = threadIdx.x;
  int lane = tid & 63, wave = tid >> 6;
  int wm = wave >> 1;                 // 0..3 : token-row group of 64
  int wn = wave & 1;                  // 0..1 : f-col group of 32
  int l15 = lane & 15, quad = lane >> 4;

  // -------- staging thread mapping: srow 0..127, chunk 0..3 (16B each)
  int srow = tid >> 2;
  int chunk = tid & 3;
  int s_sw = (srow & 3) ^ ((srow >> 2) & 3);
  int g_chunk = ((chunk ^ s_sw) * 8);      // element offset of swizzled chunk

  const int* idxe = idx + e * CAP + mt * 256;
  int tok0 = idxe[srow];
  int tok1 = idxe[srow + 128];
  const ushort_t* pA0 = xb + (size_t)tok0 * HDIM + g_chunk;
  const ushort_t* pA1 = xb + (size_t)tok1 * HDIM + g_chunk;
  const ushort_t* pB = (srow < 64)
      ? (w1t + ((size_t)e * FDIM + f0 + srow) * HDIM + g_chunk)
      : (w3t + ((size_t)e * FDIM + f0 + (srow - 64)) * HDIM + g_chunk);

  // -------- ds_read fragment offsets (bf16 elems, buffer-relative)
  int aoff[4], b1off[2];
#pragma unroll
  for (int mi = 0; mi < 4; ++mi) {
    int R = wm * 64 + mi * 16 + l15;
    int sw = (R & 3) ^ ((R >> 2) & 3);
    aoff[mi] = R * 32 + ((quad ^ sw) * 8);
  }
#pragma unroll
  for (int nj = 0; nj < 2; ++nj) {
    int r1 = wn * 32 + nj * 16 + l15;     // w1 rows at tile rows 0..63
    int sw = (r1 & 3) ^ ((r1 >> 2) & 3);  // same swizzle for r1+64 (w3 rows)
    b1off[nj] = 8192 + r1 * 32 + ((quad ^ sw) * 8);
  }

  f32x4 acc1[4][2], acc3[4][2];
#pragma unroll
  for (int i = 0; i < 4; ++i)
#pragma unroll
    for (int j = 0; j < 2; ++j) {
      acc1[i][j] = (f32x4){0.f, 0.f, 0.f, 0.f};
      acc3[i][j] = (f32x4){0.f, 0.f, 0.f, 0.f};
    }

  // -------- prologue: stage K-tiles 0,1 ; pointers end at K-tile 2
  G1_STAGE(0); pA0 += 32; pA1 += 32; pB += 32;
  G1_STAGE(1); pA0 += 32; pA1 += 32; pB += 32;

  // -------- main loop: 32 K-tiles; iter t consumes buf[t%3], prefetches t+2
  for (int it = 0; it < 10; ++it) {
    G1_ITER(0, 2, "3", 1)
    G1_ITER(1, 0, "3", 1)
    G1_ITER(2, 1, "3", 1)
  }
  G1_ITER(0, 0, "3", 0)   // t=30
  G1_ITER(1, 0, "0", 0)   // t=31 (final: drain)

  // -------- epilogue: silu(a)*g, lane-local; C/D: col=l15, row=quad*4+reg
  ushort_t* hb = hidden + ((size_t)e * CAP + mt * 256) * FDIM + f0;
#pragma unroll
  for (int mi = 0; mi < 4; ++mi)
#pragma unroll
    for (int nj = 0; nj < 2; ++nj)
#pragma unroll
      for (int r = 0; r < 4; ++r) {
        int row = wm * 64 + mi * 16 + quad * 4 + r;
        int col = wn * 32 + nj * 16 + l15;
        float v1 = acc1[mi][nj][r];
        float v3 = acc3[mi][nj][r];
        float s = (v1 / (1.f + __expf(-v1))) * v3;
        hb[(size_t)row * FDIM + col] = f2b(s);
      }
}

// ------------------------------------- GEMM2: hidden @ w2 -> weighted store (no atomics)
// Ring-3 counted-vmcnt: 128x128 tile, BK=32, 512 thr (8 waves = 2M x 4N),
// 48 KB LDS. vmcnt(2) steady state. XCD swizzle (640 = 8x80).
#define G2_STAGE(BB) \
  gl_lds16(pA, lds2 + (BB)*8192 + (size_t)tid*8); \
  gl_lds16(pB, lds2 + (BB)*8192 + 4096 + (size_t)tid*8);

#define G2_ITER(CB, PB, VM, PREF) { \
  asm volatile("s_waitcnt vmcnt(" VM ")" ::: "memory"); \
  __builtin_amdgcn_s_barrier(); \
  if (PREF) { G2_STAGE(PB); pA += 32; pB += 32; } \
  bf16x8 af[4], bf[2]; \
  _Pragma("unroll") \
  for (int mi = 0; mi < 4; ++mi) af[mi] = *(const bf16x8*)(lds2 + (CB)*8192 + aoff[mi]); \
  _Pragma("unroll") \
  for (int nj = 0; nj < 2; ++nj) bf[nj] = *(const bf16x8*)(lds2 + (CB)*8192 + boff[nj]); \
  __builtin_amdgcn_s_setprio(1); \
  _Pragma("unroll") \
  for (int mi = 0; mi < 4; ++mi) \
    _Pragma("unroll") \
    for (int nj = 0; nj < 2; ++nj) \
      acc[mi][nj] = __builtin_amdgcn_mfma_f32_16x16x32_bf16(af[mi], bf[nj], acc[mi][nj], 0, 0, 0); \
  __builtin_amdgcn_s_setprio(0); \
}

__global__ void __launch_bounds__(512) gemm2_k(
    const ushort_t* __restrict__ hidden, // [E][CAP][FDIM]
    const ushort_t* __restrict__ w2t,    // [E][HDIM][FDIM]
    const float* __restrict__ ex, const float* __restrict__ expsum,
    float* __restrict__ oute)            // [E][CAP][HDIM] fp32, weighted
{
  int bb = blockIdx.x;
  int b = (bb & 7) * 80 + (bb >> 3);    // XCD-bijective swizzle (nwg=640)
  int nt = b & 7; int t1 = b >> 3; int mt = t1 % 10; int e = t1 / 10;

  // 3 ring buffers x (A 128x32 = 4096 el | B 128x32 = 4096 el) = 48 KB
  __shared__ __bf16 lds2[3 * 8192];
  __shared__ float wgts[128];

  int tid = threadIdx.x;
  int lane = tid & 63, wave = tid >> 6;
  int wm = wave >> 2;                 // 0..1 : hidden-slot group of 64
  int wn = wave & 3;                  // 0..3 : h-col group of 32
  int l15 = lane & 15, quad = lane >> 4;

  if (tid < 128) wgts[tid] = ex[e * CAP + mt * 128 + tid] / expsum[e];

  // -------- staging: srow 0..127, chunk 0..3 (16B each)
  int srow = tid >> 2;
  int chunk = tid & 3;
  int s_sw = (srow & 3) ^ ((srow >> 2) & 3);
  int g_chunk = ((chunk ^ s_sw) * 8);

  const ushort_t* pA = hidden + ((size_t)e * CAP + mt * 128 + srow) * FDIM + g_chunk;
  const ushort_t* pB = w2t + ((size_t)e * HDIM + nt * 128 + srow) * FDIM + g_chunk;

  // -------- ds_read fragment offsets (bf16 elems, buffer-relative)
  int aoff[4], boff[2];
#pragma unroll
  for (int mi = 0; mi < 4; ++mi) {
    int R = wm * 64 + mi * 16 + l15;
    int sw = (R & 3) ^ ((R >> 2) & 3);
    aoff[mi] = R * 32 + ((quad ^ sw) * 8);
  }
#pragma unroll
  for (int nj = 0; nj < 2; ++nj) {
    int r2 = wn * 32 + nj * 16 + l15;
    int sw = (r2 & 3) ^ ((r2 >> 2) & 3);
    boff[nj] = 4096 + r2 * 32 + ((quad ^ sw) * 8);
  }

  f32x4 acc[4][2];
#pragma unroll
  for (int i = 0; i < 4; ++i)
#pragma unroll
    for (int j = 0; j < 2; ++j) acc[i][j] = (f32x4){0.f, 0.f, 0.f, 0.f};

  // -------- prologue: stage K-tiles 0,1
  G2_STAGE(0); pA += 32; pB += 32;
  G2_STAGE(1); pA += 32; pB += 32;

  // -------- main loop: 64 K-tiles (FDIM/32)
  for (int it = 0; it < 20; ++it) {
    G2_ITER(0, 2, "2", 1)
    G2_ITER(1, 0, "2", 1)
    G2_ITER(2, 1, "2", 1)
  }
  G2_ITER(0, 2, "2", 1)   // t=60, pref t62
  G2_ITER(1, 0, "2", 1)   // t=61, pref t63
  G2_ITER(2, 0, "2", 0)   // t=62
  G2_ITER(0, 0, "0", 0)   // t=63 (final: drain)

  float* ob = oute + ((size_t)e * CAP + mt * 128) * HDIM + nt * 128;
#pragma unroll
  for (int mi = 0; mi < 4; ++mi)
#pragma unroll
    for (int nj = 0; nj < 2; ++nj)
#pragma unroll
      for (int rr = 0; rr < 4; ++rr) {
        int row = wm * 64 + mi * 16 + quad * 4 + rr;
        int col = wn * 32 + nj * 16 + l15;
        ob[(size_t)row * HDIM + col] = acc[mi][nj][rr] * wgts[row];
      }
}

// ---------------------------------------- combine: per-token gather-sum -> y
__global__ void __launch_bounds__(256) combine_k(
    const float* __restrict__ oute,      // [E][CAP][HDIM] weighted
    const int* __restrict__ tok_cnt, const int* __restrict__ tok_ent,
    float* __restrict__ y)               // [T_TOK][HDIM]
{
  int t = blockIdx.x;
  int c = threadIdx.x * 4;
  int n = tok_cnt[t];
  float4 acc = {0.f, 0.f, 0.f, 0.f};
  for (int i = 0; i < n; ++i) {
    int ent = tok_ent[t * 8 + i];
    int e = ent >> 16, slot = ent & 0xffff;
    float4 v = *(const float4*)(oute + (((size_t)e * CAP + slot) << 10) + c);
    acc.x += v.x; acc.y += v.y; acc.z += v.z; acc.w += v.w;
  }
  *(float4*)(y + ((size_t)t << 10) + c) = acc;
}

// --------------------------------------------------------------------- launch
extern "C" void kernel_launch(void* const* d_in, const int* in_sizes, int n_in,
                              void* d_out, int out_size, void* d_ws, size_t ws_size,
                              hipStream_t stream)
{
  const float* x  = (const float*)d_in[0];
  const float* gw = (const float*)d_in[1];
  const float* w1 = (const float*)d_in[2];
  const float* w2 = (const float*)d_in[3];
  const float* w3 = (const float*)d_in[4];
  float* y = (float*)d_out;

  char* ws = (char*)d_ws;
  float*    logitsT = (float*)(ws + 0x0);          // 256 KB [E][T]
  int*      idx     = (int*)(ws + 0x40000);        // 40 KB
  float*    exo     = (float*)(ws + 0x4A000);      // 40 KB
  unsigned* thr    = (unsigned*)(ws + 0x54000);    // ctrl block (zeroed): 256 B
  int*      need   = (int*)(ws + 0x54020);
  unsigned* umax   = (unsigned*)(ws + 0x54040);
  int*      cnt    = (int*)(ws + 0x54060);
  int*      tie    = (int*)(ws + 0x54080);
  float*    expsum = (float*)(ws + 0x540A0);
  int*      tok_cnt = (int*)(ws + 0x55000);        // 32 KB
  int*      tok_ent = (int*)(ws + 0x5D000);        // 256 KB
  ushort_t* xb     = (ushort_t*)(ws + 0xA0000);    // 16 MB  [T][H] bf16
  ushort_t* w1t    = (ushort_t*)(ws + 0x10A0000);  // 32 MB  [E][F][H]
  ushort_t* w3t    = (ushort_t*)(ws + 0x30A0000);  // 32 MB
  ushort_t* w2t    = (ushort_t*)(ws + 0x50A0000);  // 32 MB  [E][H][F]
  ushort_t* hid    = (ushort_t*)(ws + 0x70A0000);  // 40 MB  [E][CAP][F]
  float*    oute   = (float*)(ws + 0x10A0000);     // 40 MB, aliases w1t+w3t (dead after gemm1)

  // tail of d_out beyond y (the scalar 0.0 output) must be zero
  size_t yelems = (size_t)T_TOK * HDIM;
  if ((size_t)out_size > yelems)
    hipMemsetAsync((char*)d_out + yelems * 4, 0, ((size_t)out_size - yelems) * 4, stream);
  hipMemsetAsync(ws + 0x54000, 0, 256, stream);

  prep_k<<<3072 + 2048, 256, 0, stream>>>(w1, w3, w2, w1t, w3t, w2t, x, gw, logitsT, xb);
  select_k<<<EXP, 256, 0, stream>>>(logitsT, thr, need, umax);
  emit_k<<<T_TOK / 256, 256, 0, stream>>>(logitsT, thr, need, umax, idx, exo, cnt, tie, expsum, tok_cnt, tok_ent);
  gemm1_swiglu_k<<<EXP * 5 * 32, 512, 0, stream>>>(xb, w1t, w3t, idx, hid);
  gemm2_k<<<EXP * 10 * 8, 512, 0, stream>>>(hid, w2t, exo, expsum, oute);
  combine_k<<<T_TOK, 256, 0, stream>>>(oute, tok_cnt, tok_ent, y);
}